// Round 9
// baseline (547.190 us; speedup 1.0000x reference)
//
#include <hip/hip_runtime.h>
#include <hip/hip_bf16.h>
#include <stdint.h>

// DH-SNN forward: two-phase optimistic execution.
// Phase 1 (free-run): each WG scans all 250 steps assuming ZERO recurrent spikes — no inter-WG
//   communication, no __syncthreads in the loop; 4 waves each own disjoint A-rows/DMA/C-rows/state.
//   B panel lives in 176 VGPRs/wave (LDS-issue was the R8 bottleneck: 78 -> 34 LDS instrs/wave/step).
//   Update drops the -spk term (zero-spike assumption) and tracks memmax; memmax>VTH = violation,
//   detection identical up to the first crossing (all state discarded on violation anyway).
// Verdict: one 8B flag/WG + one poll of own batch-half (batch rows are independent sub-problems).
// Phase 2 (rare fallback): if any spike occurred, re-init state and run the synchronous
//   wave-specialized algorithm (R7), tags shifted (+1) to avoid phase-1 collisions.

typedef short short8 __attribute__((ext_vector_type(8)));
typedef float f32x4 __attribute__((ext_vector_type(4)));

#define T_STEPS 250
#define BATCH   128
#define HID     1024
#define NCOL    4096      // HID*BRANCH
#define IND     700
#define ISZ     1724
#define KPAD    704
#define OUTD    20
#define NWG     256
#define WGT     256
#define UPB     5632      // 16B units per (t,half) A block = 64*704*2/16

// ws layout (bytes)
#define O_P1F   0                // u64[2 half][128 wg] phase-1 flags = 2048 B
#define O_SUM   2048             // u64[2 parity][2 half][128 wg] = 4096 B
#define O_CHK   6144             // u64[2 parity][2 half][128 wg][16 chunks] = 65536 B
#define O_WST   71680            // f32 [1024][4096] = 16777216 B
#define O_WXH   16848896         // bf16 [4096][704] = 5767168 B
#define O_XH    22616064         // bf16 [250][2][5632][8] swizzled = 45056000 B (end ~67.7 MB)

#define AGENT __HIP_MEMORY_SCOPE_AGENT

__device__ __forceinline__ float sigmoidf(float x) { return 1.0f / (1.0f + expf(-x)); }

__device__ __forceinline__ unsigned ldsLd(const unsigned* p) {
    return __hip_atomic_load(p, __ATOMIC_ACQUIRE, __HIP_MEMORY_SCOPE_WORKGROUP);
}
__device__ __forceinline__ void ldsSt(unsigned* p, unsigned v) {
    __hip_atomic_store(p, v, __ATOMIC_RELEASE, __HIP_MEMORY_SCOPE_WORKGROUP);
}

__device__ __forceinline__ void dma16(const void* g, void* l) {
    __builtin_amdgcn_global_load_lds(
        (const __attribute__((address_space(1))) unsigned int*)g,
        (__attribute__((address_space(3))) unsigned int*)l, 16, 0, 0);
}

// x -> Xh, pre-swizzled so a LINEAR global_load_lds DMA yields the bank-conflict-free
// LDS layout: unit q (16B) of block (t,half) holds elements (row=q/88, k=((q%88)^(row&7))*8+e).
__global__ void prep_x(const float* __restrict__ x, __hip_bfloat16* __restrict__ Xh) {
    const int total = T_STEPS * 2 * UPB;
    for (int unit = blockIdx.x * blockDim.x + threadIdx.x; unit < total;
         unit += gridDim.x * blockDim.x) {
        int q   = unit % UPB;
        int blk = unit / UPB;          // t*2 + half
        int half = blk & 1, t = blk >> 1;
        int row = q / 88, m = q % 88;
        int k8  = m ^ (row & 7);
        int b   = half * 64 + row;
        const float* xp = x + ((long)b * T_STEPS + t) * IND + k8 * 8;
        short8 o;
        #pragma unroll
        for (int e = 0; e < 8; ++e) {
            int k = k8 * 8 + e;
            float v = (k < IND) ? xp[e] : 0.0f;
            union { __hip_bfloat16 h; short s; } u;
            u.h = __float2bfloat16(v);
            o[e] = u.s;
        }
        *(short8*)(Xh + (size_t)unit * 8) = o;
    }
}

__global__ void prep_w(const float* __restrict__ W, __hip_bfloat16* __restrict__ Wxh,
                       uint64_t* __restrict__ p1f, uint64_t* __restrict__ sums,
                       uint64_t* __restrict__ chunks) {
    if (blockIdx.x == 0) {       // zero exchange area every launch (replay staleness + 0xAA poison)
        for (int i = threadIdx.x; i < 2 * 128; i += blockDim.x)
            __hip_atomic_store(&p1f[i], 0ull, __ATOMIC_RELAXED, AGENT);
        for (int i = threadIdx.x; i < 2 * 2 * 128; i += blockDim.x)
            __hip_atomic_store(&sums[i], 0ull, __ATOMIC_RELAXED, AGENT);
        for (int i = threadIdx.x; i < 2 * 2 * 128 * 16; i += blockDim.x)
            __hip_atomic_store(&chunks[i], 0ull, __ATOMIC_RELAXED, AGENT);
    }
    const int total = NCOL * KPAD;
    for (int idx = blockIdx.x * blockDim.x + threadIdx.x; idx < total; idx += gridDim.x * blockDim.x) {
        int k = idx % KPAD;
        int n = idx / KPAD;
        float v = (k < IND) ? W[(long)n * ISZ + k] : 0.0f;
        Wxh[idx] = __float2bfloat16(v);
    }
}

// Wst[h][n] = W[n][700+h]   (tiled transpose)
__global__ __launch_bounds__(256) void prep_t(const float* __restrict__ W, float* __restrict__ Wst) {
    __shared__ float tile[32][33];
    const int h0 = blockIdx.x * 32, n0 = blockIdx.y * 32;
    const int tx = threadIdx.x, ty = threadIdx.y;  // (32,8)
    #pragma unroll
    for (int j = 0; j < 32; j += 8)
        tile[ty + j][tx] = W[(long)(n0 + ty + j) * ISZ + IND + h0 + tx];
    __syncthreads();
    #pragma unroll
    for (int j = 0; j < 32; j += 8)
        Wst[(long)(h0 + ty + j) * NCOL + n0 + tx] = tile[tx][ty + j];
}

__global__ __launch_bounds__(256, 1) void snn_scan(
    const __hip_bfloat16* __restrict__ Xh, const __hip_bfloat16* __restrict__ Wxh,
    const float* __restrict__ Wst, uint64_t* __restrict__ p1f, uint64_t* __restrict__ sums,
    uint64_t* __restrict__ chunks,
    const float* __restrict__ bvec, const float* __restrict__ tau_m, const float* __restrict__ tau_n,
    const float* __restrict__ Wr, const float* __restrict__ brv, const float* __restrict__ tau_r,
    const float* __restrict__ mem0, float* __restrict__ out)
{
    __shared__ __hip_bfloat16 Bp[32 * 712];   // 45568 B  Wx^T panel
    __shared__ uint8_t ApreB[90112];          // 90112 B  A[t] slice, swizzled, DMA target
    __shared__ float curL[64 * 36];           //  9216 B  C exchange, pad 36
    __shared__ uint8_t mTb[64 * 136];         //  8704 B  transposed masks, ~all-zero
    __shared__ uint32_t stageW[16];           // spike bytes (phase 2)
    __shared__ uint64_t roSnap[16];           // readout-row snapshot (phase 2)
    __shared__ unsigned fPollDone[2];         // (k<<1)|any, per poll wave (phase 2)
    __shared__ unsigned fStgw[2], fCorr[2];   // per compute wave (phase 2)
    __shared__ unsigned fRoSnap;              // (phase 2)
    __shared__ unsigned anySpkF, p1dirty;     // phase-1 verdict

    const int wg    = blockIdx.x;     // 0..255
    const int w     = wg & 127;       // column group: cols [w*32, w*32+32)
    const int bhalf = wg >> 7;        // batches [0,64) or [64,128)
    const int bbase = bhalf * 64;
    const int c0    = w * 32;
    const int i0    = w * 8;
    const int tid   = threadIdx.x;
    const int lane  = tid & 63, wid = tid >> 6;

    // stage B panel into LDS + zero mTb + init flags
    for (int idx = tid; idx < 32 * KPAD; idx += WGT) {
        int col = idx / KPAD, k = idx % KPAD;
        Bp[col * 712 + k] = Wxh[(long)(c0 + col) * KPAD + k];
    }
    for (int idx = tid; idx < 64 * 136 / 4; idx += WGT)
        ((uint32_t*)mTb)[idx] = 0u;
    if (tid < 2) { fPollDone[tid] = 0; fStgw[tid] = 0; fCorr[tid] = 0; }
    if (tid == 0) { fRoSnap = 0; anySpkF = 0; p1dirty = 0; }

    // readout: rows 0..63 -> wg 0..63; rows 64..127 -> wg 128..191 (same batch half)
    const int roB = (wg < 64) ? wg : ((wg >= 128 && wg < 192) ? wg - 64 : -1);
    float r_alpha = 0.f, r_bias = 0.f, r_rmem = 0.f, r_acc = 0.f;
    const float* WrRow = Wr;
    if (wid == 0 && roB >= 0 && lane < 32) {
        int o = (lane < OUTD) ? lane : 0;
        r_alpha = sigmoidf(tau_r[o]);
        r_bias  = brv[o];
        WrRow   = Wr + o * HID;
    }

    // ---------------- phase-1 state: 2 neurons x 4 branches, one batch row ----------------
    const int r  = tid >> 2;          // local batch row 0..63  (wave w owns rows [16w,16w+16))
    const int nq = tid & 3;
    const int b  = bbase + r;
    float dn[8], bt[8], omb[8], bias[8], alph[2], oma[2], mem[2];
    #pragma unroll
    for (int m = 0; m < 2; ++m) {
        int i = i0 + nq * 2 + m;
        alph[m] = sigmoidf(tau_m[i]);
        oma[m]  = 1.0f - alph[m];
        mem[m]  = mem0[b * HID + i];
        #pragma unroll
        for (int j = 0; j < 4; ++j) {
            bt[m * 4 + j]   = sigmoidf(tau_n[i * 4 + j]);
            omb[m * 4 + j]  = 1.0f - bt[m * 4 + j];
            bias[m * 4 + j] = bvec[i * 4 + j];
            dn[m * 4 + j]   = 0.0f;
        }
    }

    // phase-1 GEMM addressing: wave wid owns A rows [wid*16, wid*16+16)
    const int kb8   = (lane >> 4) * 8;
    const int colA  = lane & 15;
    const int p1row = wid * 16 + (lane & 15);
    const int sw1   = p1row & 7;
    uint8_t* dst1   = ApreB + wid * 22528;    // own 16 rows x 1408 B

    // prologue: each wave DMAs its own 16 rows of A[0]
    {
        const char* gsrc = (const char*)Xh + ((size_t)bhalf * UPB) * 16 + (size_t)wid * 22528;
        #pragma unroll
        for (int i = 0; i < 22; ++i)
            dma16(gsrc + i * 1024 + lane * 16, dst1 + i * 1024);
    }
    asm volatile("s_waitcnt vmcnt(0)" ::: "memory");
    __syncthreads();

    // B panel -> registers (static across all 250 steps; kills 44 of 78 LDS instrs/wave/step)
    short8 Breg[44];
    #pragma unroll
    for (int i = 0; i < 22; ++i) {
        Breg[2 * i]     = *(const short8*)(&Bp[(colA) * 712 + i * 32 + kb8]);
        Breg[2 * i + 1] = *(const short8*)(&Bp[(16 + colA) * 712 + i * 32 + kb8]);
    }

    // ================= PHASE 1: optimistic free-run (no inter-WG, no intra-WG barriers) =======
    float memmax = -1e30f;
    for (int t = 0; t < T_STEPS; ++t) {
        f32x4 acc0 = {0,0,0,0}, acc1 = {0,0,0,0};
        #pragma unroll
        for (int i = 0; i < 22; ++i) {
            int k8 = i * 4 + (lane >> 4);
            short8 f0 = *(const short8*)&ApreB[((p1row * 88 + (k8 ^ sw1)) << 4)];
            acc0 = __builtin_amdgcn_mfma_f32_16x16x32_bf16(f0, Breg[2 * i], acc0, 0, 0, 0);
            acc1 = __builtin_amdgcn_mfma_f32_16x16x32_bf16(f0, Breg[2 * i + 1], acc1, 0, 0, 0);
        }
        asm volatile("s_waitcnt lgkmcnt(0)" ::: "memory");
        __builtin_amdgcn_sched_barrier(0);
        if (t + 1 < T_STEPS) {   // DMA own rows of A[t+1]
            const char* gsrc = (const char*)Xh
                + (((size_t)(t + 1) * 2 + bhalf) * UPB) * 16 + (size_t)wid * 22528;
            #pragma unroll
            for (int i = 0; i < 22; ++i)
                dma16(gsrc + i * 1024 + lane * 16, dst1 + i * 1024);
        }
        {   // C -> curL (own rows only; consumed by own wave's threads)
            const int crow0 = wid * 16 + ((lane >> 4) << 2);
            #pragma unroll
            for (int j = 0; j < 4; ++j) {
                curL[(crow0 + j) * 36 + colA]      = acc0[j];
                curL[(crow0 + j) * 36 + 16 + colA] = acc1[j];
            }
        }
        asm volatile("s_waitcnt lgkmcnt(0)" ::: "memory");
        __builtin_amdgcn_sched_barrier(0);
        {   // zero-spike update (no -spk term; violation tracked via memmax)
            const float* cl = &curL[r * 36 + nq * 8];
            #pragma unroll
            for (int m = 0; m < 2; ++m) {
                float lin = 0.f;
                #pragma unroll
                for (int j = 0; j < 4; ++j) {
                    int idx = m * 4 + j;
                    dn[idx] = bt[idx] * dn[idx] + omb[idx] * (cl[idx] + bias[idx]);
                    lin += dn[idx];
                }
                float mm = alph[m] * mem[m] + oma[m] * lin;   // VTH=1; spk==0 assumed
                mem[m] = mm;
                memmax = fmaxf(memmax, mm);
            }
        }
        // readout for step s=t assuming zero spikes (rsum = 0)
        if (wid == 0 && roB >= 0 && lane < 32) {
            r_rmem = r_alpha * r_rmem + (1.0f - r_alpha) * (0.0f + r_bias);
            float vmax = (lane < OUTD) ? r_rmem : -__builtin_inff();
            #pragma unroll
            for (int d = 16; d > 0; d >>= 1) vmax = fmaxf(vmax, __shfl_xor(vmax, d, 32));
            float e = (lane < OUTD) ? expf(r_rmem - vmax) : 0.f;
            float ssum = e;
            #pragma unroll
            for (int d = 16; d > 0; d >>= 1) ssum += __shfl_xor(ssum, d, 32);
            if (t >= 1) r_acc += e / ssum;   // WARMUP=0: accumulate for s>=1
        }
        asm volatile("s_waitcnt vmcnt(0)" ::: "memory");   // own DMA arrived
    }

    // ---------------- phase-1 verdict ----------------
    if (__any(memmax > 1.0f) && lane == 0) anySpkF = 1u;
    __syncthreads();
    const unsigned wgDirty = anySpkF;
    if (tid == 0)
        __hip_atomic_store(p1f + (size_t)bhalf * 128 + w,
                           (1ull << 32) | (uint64_t)wgDirty, __ATOMIC_RELAXED, AGENT);
    if (tid < 128) {   // poll own half's 128 flags (batch halves are independent)
        const uint64_t* fp = p1f + (size_t)bhalf * 128 + tid;
        uint64_t v;
        for (;;) {
            v = __hip_atomic_load(fp, __ATOMIC_RELAXED, AGENT);
            if ((unsigned)(v >> 32) == 1u) break;
            __builtin_amdgcn_s_sleep(1);
        }
        if (__any((unsigned)v != 0u) && lane == 0) ldsSt(&p1dirty, 1u);
    }
    __syncthreads();
    if (p1dirty == 0) {   // clean: phase-1 trajectories are exact -> done
        if (wid == 0 && roB >= 0 && lane < OUTD) out[roB * OUTD + lane] = r_acc;
        return;
    }

    // ================= PHASE 2: synchronous fallback (R7 algorithm, tags +1) =================
    r_rmem = 0.f; r_acc = 0.f;

    // compute-wave state: 4 neurons x 4 branches (waves 2,3)
    const int mwid = wid - 2;
    const int st   = tid - 128;
    const int r2   = st >> 1;
    const int half = st & 1;
    float dn2[16], bt2[16], omb2[16], bias2[16], alph2[4], oma2[4], mem2[4], spk2[4];
    if (wid >= 2) {
        const int b2 = bbase + r2;
        #pragma unroll
        for (int n = 0; n < 4; ++n) {
            int i = i0 + half * 4 + n;
            alph2[n] = sigmoidf(tau_m[i]);
            oma2[n]  = 1.0f - alph2[n];
            mem2[n]  = mem0[b2 * HID + i];
            spk2[n]  = 0.0f;
            #pragma unroll
            for (int j = 0; j < 4; ++j) {
                int idx = n * 4 + j;
                bt2[idx]   = sigmoidf(tau_n[i * 4 + j]);
                omb2[idx]  = 1.0f - bt2[idx];
                bias2[idx] = bvec[i * 4 + j];
                dn2[idx]   = 0.0f;
            }
        }
    }
    const int trRow = mwid * 32;
    const int rb2   = trRow + (lane & 15);
    const int sw2   = rb2 & 7;
    uint8_t* dst2   = ApreB + mwid * 45056;

    if (wid >= 2) {   // re-prologue A[0]
        const char* gsrc = (const char*)Xh + ((size_t)bhalf * UPB) * 16 + (size_t)mwid * 45056;
        #pragma unroll
        for (int i = 0; i < 44; ++i)
            dma16(gsrc + i * 1024 + lane * 16, dst2 + i * 1024);
    }
    asm volatile("s_waitcnt vmcnt(0)" ::: "memory");
    __syncthreads();

    if (wid < 2) {
        // ---- poll waves ----
        const int plane = tid;
        for (int k = 1; k <= T_STEPS; ++k) {
            const size_t base = ((size_t)((k - 1) & 1) * 2 + bhalf) * 128 + plane;
            const unsigned want = (unsigned)(k + 1);
            uint64_t v;
            for (;;) {
                v = __hip_atomic_load(sums + base, __ATOMIC_RELAXED, AGENT);
                if ((unsigned)(v >> 32) == want) break;
                __builtin_amdgcn_s_sleep(1);
            }
            unsigned mysum = (unsigned)v;
            if (mysum) {
                if (wid == 1)
                    while (ldsLd(&fRoSnap) < (unsigned)(k - 1)) {}
                const uint64_t* rec = chunks + base * 16;
                uint8_t* col = mTb + plane;
                unsigned pend = mysum;
                while (pend) {
                    int c = __builtin_ctz(pend);
                    uint64_t cv = __hip_atomic_load(rec + c, __ATOMIC_RELAXED, AGENT);
                    if ((unsigned)(cv >> 32) == want) {
                        pend &= pend - 1;
                        unsigned pay = (unsigned)cv;
                        col[(4 * c + 0) * 136] = (uint8_t)(pay);
                        col[(4 * c + 1) * 136] = (uint8_t)(pay >> 8);
                        col[(4 * c + 2) * 136] = (uint8_t)(pay >> 16);
                        col[(4 * c + 3) * 136] = (uint8_t)(pay >> 24);
                    } else {
                        __builtin_amdgcn_s_sleep(1);
                    }
                }
            }
            const bool anyW = __any(mysum != 0u);
            if (lane == 0)
                ldsSt(&fPollDone[wid], ((unsigned)k << 1) | (anyW ? 1u : 0u));

            if (wid == 0) {
                while ((ldsLd(&fPollDone[1]) >> 1) < (unsigned)k) {}
                if (roB >= 0 && lane < 16)
                    roSnap[lane] = ((const uint64_t*)(mTb + (roB & 63) * 136))[lane];
                asm volatile("s_waitcnt lgkmcnt(0)" ::: "memory");
                if (lane == 0) ldsSt(&fRoSnap, (unsigned)k);
                if (roB >= 0 && lane < 32) {
                    float rsum = 0.f;
                    #pragma unroll 4
                    for (int q = 0; q < 16; ++q) {
                        uint64_t mword = roSnap[q];
                        while (mword) {
                            int h = (q << 6) + __builtin_ctzll(mword);
                            mword &= mword - 1;
                            rsum += WrRow[h];
                        }
                    }
                    r_rmem = r_alpha * r_rmem + (1.0f - r_alpha) * (rsum + r_bias);
                    float vmax = (lane < OUTD) ? r_rmem : -__builtin_inff();
                    #pragma unroll
                    for (int d = 16; d > 0; d >>= 1) vmax = fmaxf(vmax, __shfl_xor(vmax, d, 32));
                    float e = (lane < OUTD) ? expf(r_rmem - vmax) : 0.f;
                    float ssum = e;
                    #pragma unroll
                    for (int d = 16; d > 0; d >>= 1) ssum += __shfl_xor(ssum, d, 32);
                    if (k >= 2) r_acc += e / ssum;
                }
            }
        }
        if (wid == 0 && roB >= 0 && lane < OUTD) out[roB * OUTD + lane] = r_acc;
    } else {
        // ---- compute waves ----
        const float* clp = &curL[r2 * 36 + half * 16];
        for (int t = 0; t < T_STEPS; ++t) {
            f32x4 a00 = {0,0,0,0}, a01 = {0,0,0,0}, a10 = {0,0,0,0}, a11 = {0,0,0,0};
            #pragma unroll
            for (int k0 = 0; k0 < KPAD; k0 += 32) {
                int k8 = (k0 >> 3) + (lane >> 4);
                short8 f0 = *(const short8*)&ApreB[(((rb2)      * 88 + (k8 ^ sw2)) << 4)];
                short8 f1 = *(const short8*)&ApreB[(((rb2 + 16) * 88 + (k8 ^ sw2)) << 4)];
                short8 b0 = *(const short8*)(&Bp[(colA) * 712 + k0 + kb8]);
                short8 b1 = *(const short8*)(&Bp[(16 + colA) * 712 + k0 + kb8]);
                a00 = __builtin_amdgcn_mfma_f32_16x16x32_bf16(f0, b0, a00, 0, 0, 0);
                a01 = __builtin_amdgcn_mfma_f32_16x16x32_bf16(f0, b1, a01, 0, 0, 0);
                a10 = __builtin_amdgcn_mfma_f32_16x16x32_bf16(f1, b0, a10, 0, 0, 0);
                a11 = __builtin_amdgcn_mfma_f32_16x16x32_bf16(f1, b1, a11, 0, 0, 0);
            }
            asm volatile("s_waitcnt lgkmcnt(0)" ::: "memory");
            __builtin_amdgcn_sched_barrier(0);
            if (t + 1 < T_STEPS) {
                const char* gsrc = (const char*)Xh
                    + (((size_t)(t + 1) * 2 + bhalf) * UPB) * 16 + (size_t)mwid * 45056;
                #pragma unroll
                for (int i = 0; i < 44; ++i)
                    dma16(gsrc + i * 1024 + lane * 16, dst2 + i * 1024);
            }
            {
                const int crow0 = trRow + ((lane >> 4) << 2);
                #pragma unroll
                for (int j = 0; j < 4; ++j) {
                    curL[(crow0 + j) * 36 + colA]           = a00[j];
                    curL[(crow0 + j) * 36 + 16 + colA]      = a01[j];
                    curL[(crow0 + 16 + j) * 36 + colA]      = a10[j];
                    curL[(crow0 + 16 + j) * 36 + 16 + colA] = a11[j];
                }
            }
            asm volatile("s_waitcnt lgkmcnt(0)" ::: "memory");
            __builtin_amdgcn_sched_barrier(0);

            f32x4 cv0 = *(const f32x4*)(clp + 0);
            f32x4 cv1 = *(const f32x4*)(clp + 4);
            f32x4 cv2 = *(const f32x4*)(clp + 8);
            f32x4 cv3 = *(const f32x4*)(clp + 12);
            float cl[16];
            #pragma unroll
            for (int e = 0; e < 4; ++e) {
                cl[e] = cv0[e]; cl[4 + e] = cv1[e]; cl[8 + e] = cv2[e]; cl[12 + e] = cv3[e];
            }
            float memS[4], spkS[4];
            #pragma unroll
            for (int n = 0; n < 4; ++n) {
                float lin = 0.f;
                #pragma unroll
                for (int j = 0; j < 4; ++j) {
                    int idx = n * 4 + j;
                    dn2[idx] = bt2[idx] * dn2[idx] + omb2[idx] * (cl[idx] + bias2[idx]);
                    lin += dn2[idx];
                }
                memS[n] = alph2[n] * mem2[n] + oma2[n] * lin - spk2[n];
                spkS[n] = (memS[n] > 1.0f) ? 1.0f : 0.0f;
            }
            unsigned nib = 0;
            #pragma unroll
            for (int n = 0; n < 4; ++n) nib |= (spkS[n] != 0.f ? 1u : 0u) << (half * 4 + n);
            nib |= (unsigned)__shfl_xor((int)nib, 1);
            if (half == 0) ((uint8_t*)stageW)[r2] = (uint8_t)nib;
            if (lane == 0) ldsSt(&fStgw[mwid], (unsigned)(t + 1));

            bool anySpk = false;
            if (t > 0) {
                unsigned p0, p1;
                do { p0 = ldsLd(&fPollDone[0]); } while ((p0 >> 1) < (unsigned)t);
                do { p1 = ldsLd(&fPollDone[1]); } while ((p1 >> 1) < (unsigned)t);
                anySpk = ((p0 | p1) & 1u) != 0u;
            }
            if (anySpk) {
                float recv[16];
                #pragma unroll
                for (int e = 0; e < 16; ++e) recv[e] = 0.f;
                const float* Wb = Wst + c0 + half * 16;
                const uint64_t* mrow = (const uint64_t*)(mTb + r2 * 136);
                for (int q = 0; q < 16; ++q) {
                    uint64_t mword = mrow[q];
                    while (mword) {
                        int h = (q << 6) + __builtin_ctzll(mword);
                        mword &= mword - 1;
                        const f32x4* wv = (const f32x4*)(Wb + (long)h * NCOL);
                        f32x4 w0 = wv[0], w1 = wv[1], w2 = wv[2], w3 = wv[3];
                        #pragma unroll
                        for (int e = 0; e < 4; ++e) {
                            recv[e] += w0[e]; recv[4 + e] += w1[e];
                            recv[8 + e] += w2[e]; recv[12 + e] += w3[e];
                        }
                    }
                }
                #pragma unroll
                for (int n = 0; n < 4; ++n) {
                    float cs = 0.f;
                    #pragma unroll
                    for (int j = 0; j < 4; ++j) {
                        int idx = n * 4 + j;
                        float ad = omb2[idx] * recv[idx];
                        dn2[idx] += ad; cs += ad;
                    }
                    memS[n] += oma2[n] * cs;
                    spkS[n] = (memS[n] > 1.0f) ? 1.0f : 0.0f;
                }
                unsigned nib2 = 0;
                #pragma unroll
                for (int n = 0; n < 4; ++n) nib2 |= (spkS[n] != 0.f ? 1u : 0u) << (half * 4 + n);
                nib2 |= (unsigned)__shfl_xor((int)nib2, 1);
                if (half == 0) ((uint8_t*)stageW)[r2] = (uint8_t)nib2;
                if (roB >= 0) while (ldsLd(&fRoSnap) < (unsigned)t) {}
                uint64_t* mz = (uint64_t*)(mTb + r2 * 136) + half * 8;
                #pragma unroll
                for (int e = 0; e < 8; ++e) mz[e] = 0;
                if (lane == 0) ldsSt(&fCorr[mwid], (unsigned)(t + 1));
            }
            #pragma unroll
            for (int n = 0; n < 4; ++n) { mem2[n] = memS[n]; spk2[n] = spkS[n]; }

            if (mwid == 0) {
                while (ldsLd(&fStgw[1]) < (unsigned)(t + 1)) {}
                if (anySpk) while (ldsLd(&fCorr[1]) < (unsigned)(t + 1)) {}
                unsigned pay = (lane < 16) ? stageW[lane] : 0u;
                const size_t pbase = ((size_t)(t & 1) * 2 + bhalf) * 128 + w;
                if (lane < 16 && pay)
                    __hip_atomic_store(chunks + pbase * 16 + lane,
                                       ((uint64_t)(unsigned)(t + 2) << 32) | (uint64_t)pay,
                                       __ATOMIC_RELAXED, AGENT);
                uint64_t bal = __ballot(pay != 0u);
                if (lane == 0)
                    __hip_atomic_store(sums + pbase,
                                       ((uint64_t)(unsigned)(t + 2) << 32) | (uint64_t)(bal & 0xFFFFull),
                                       __ATOMIC_RELAXED, AGENT);
            }
            asm volatile("s_waitcnt vmcnt(0)" ::: "memory");
        }
    }
}

extern "C" void kernel_launch(void* const* d_in, const int* in_sizes, int n_in,
                              void* d_out, int out_size, void* d_ws, size_t ws_size,
                              hipStream_t stream) {
    (void)in_sizes; (void)n_in; (void)out_size; (void)ws_size;
    const float* x     = (const float*)d_in[0];
    const float* W     = (const float*)d_in[1];
    const float* bv    = (const float*)d_in[2];
    const float* tau_m = (const float*)d_in[3];
    const float* tau_n = (const float*)d_in[4];
    const float* Wr    = (const float*)d_in[5];
    const float* br    = (const float*)d_in[6];
    const float* tau_r = (const float*)d_in[7];
    const float* mem0  = (const float*)d_in[8];

    char* ws = (char*)d_ws;
    uint64_t*        p1flag = (uint64_t*)(ws + O_P1F);
    uint64_t*        sums   = (uint64_t*)(ws + O_SUM);
    uint64_t*        chunks = (uint64_t*)(ws + O_CHK);
    float*           Wst    = (float*)(ws + O_WST);
    __hip_bfloat16*  Wxh    = (__hip_bfloat16*)(ws + O_WXH);
    __hip_bfloat16*  Xh     = (__hip_bfloat16*)(ws + O_XH);

    prep_x<<<2048, 256, 0, stream>>>(x, Xh);
    prep_w<<<2048, 256, 0, stream>>>(W, Wxh, p1flag, sums, chunks);
    dim3 g3(32, 128), b3(32, 8);
    prep_t<<<g3, b3, 0, stream>>>(W, Wst);
    snn_scan<<<NWG, WGT, 0, stream>>>(Xh, Wxh, Wst, p1flag, sums, chunks,
                                      bv, tau_m, tau_n, Wr, br, tau_r, mem0, (float*)d_out);
}

// Round 10
// 523.404 us; speedup vs baseline: 1.0454x; 1.0454x over previous
//
#include <hip/hip_runtime.h>
#include <hip/hip_bf16.h>
#include <stdint.h>

// DH-SNN forward: two-phase optimistic execution, v2 decomposition.
// Phase 1 (free-run): WG = 16 batch rows (rtile=wg&7) x 128 cols (ctile=wg>>3).
//   - B panel (128 cols) lives entirely in VGPRs (176/wave, asm-pinned).
//   - A slice (16 rows, 22.5 KB/step) triple-buffered in LDS, DMA'd 2 steps ahead with
//     counted vmcnt (never 0 in-loop). One raw s_barrier per step (curL dbuf kills the 2nd).
//   - Zero-spike speculative update; memmax>VTH = violation (rows are independent sub-problems).
//   - rtile==XCD under round-robin mapping -> per-XCD L2 refetch 22.5 KB/step (was ~1 MB HBM/step).
// Verdict: 256 single-hop flags; clean half -> write out; dirty half -> phase 2.
// Phase 2 (rare fallback, old 64rowx32col decomposition, verbatim from R7/R9): Bp staging and
//   mTb zeroing deferred to phase-2 entry so the hot path never pays them.

typedef short short8 __attribute__((ext_vector_type(8)));
typedef float f32x4 __attribute__((ext_vector_type(4)));

#define T_STEPS 250
#define BATCH   128
#define HID     1024
#define NCOL    4096
#define IND     700
#define ISZ     1724
#define KPAD    704
#define OUTD    20
#define NWG     256
#define WGT     256
#define UPB     5632      // 16B units per (t,half64) A block

// ws layout (bytes)
#define O_P1F   0                // u64[256] phase-1 flags (idx = rtile*32+ctile)
#define O_SUM   2048             // u64[2 parity][2 half][128 wg]
#define O_CHK   6144             // u64[2][2][128][16]
#define O_WST   71680            // f32 [1024][4096]
#define O_WXH   16848896         // bf16 [4096][704]
#define O_XH    22616064         // bf16 [250][2][5632][8] swizzled

// smem layout (one static arena, phase-1/phase-2 regions alias deliberately)
#define SM_BP    0                       // 45568: Wx^T panel (phase 2 only)
#define SM_A2    45568                   // phase2 ApreB 90112 ; phase1 uses it as:
#define SM_CURL1 (SM_A2 + 3 * 22528)     //   3x22528 A bufs + 2x8448 curl1  (ends 130048)
#define SM_CURL2 135680                  // 9216  phase2 C exchange
#define SM_MTB   144896                  // 8704  phase2 masks
#define SM_TOTAL 153600

#define AGENT __HIP_MEMORY_SCOPE_AGENT

__device__ __forceinline__ float sigmoidf(float x) { return 1.0f / (1.0f + expf(-x)); }

__device__ __forceinline__ unsigned ldsLd(const unsigned* p) {
    return __hip_atomic_load(p, __ATOMIC_ACQUIRE, __HIP_MEMORY_SCOPE_WORKGROUP);
}
__device__ __forceinline__ void ldsSt(unsigned* p, unsigned v) {
    __hip_atomic_store(p, v, __ATOMIC_RELEASE, __HIP_MEMORY_SCOPE_WORKGROUP);
}

__device__ __forceinline__ void dma16(const void* g, void* l) {
    __builtin_amdgcn_global_load_lds(
        (const __attribute__((address_space(1))) unsigned int*)g,
        (__attribute__((address_space(3))) unsigned int*)l, 16, 0, 0);
}

// issue this wave's share (5-6 units) of a 16-row A slice DMA
__device__ __forceinline__ void issueA(const __hip_bfloat16* Xh, int t, int halfI,
                                       size_t sliceOff, uint8_t* dbuf, int wid, int lane) {
    const char* g = (const char*)Xh + (((size_t)t * 2 + halfI) * (size_t)UPB) * 16 + sliceOff;
    #pragma unroll
    for (int i = 0; i < 6; ++i) {
        int j = wid + 4 * i;
        if (j < 22) dma16(g + (size_t)j * 1024 + (size_t)lane * 16, dbuf + j * 1024);
    }
}

// x -> Xh, pre-swizzled: unit q of block (t,half64) holds (row=q/88, k=((q%88)^(row&7))*8+e).
__global__ void prep_x(const float* __restrict__ x, __hip_bfloat16* __restrict__ Xh) {
    const int total = T_STEPS * 2 * UPB;
    for (int unit = blockIdx.x * blockDim.x + threadIdx.x; unit < total;
         unit += gridDim.x * blockDim.x) {
        int q   = unit % UPB;
        int blk = unit / UPB;
        int half = blk & 1, t = blk >> 1;
        int row = q / 88, m = q % 88;
        int k8  = m ^ (row & 7);
        int b   = half * 64 + row;
        const float* xp = x + ((long)b * T_STEPS + t) * IND + k8 * 8;
        short8 o;
        #pragma unroll
        for (int e = 0; e < 8; ++e) {
            int k = k8 * 8 + e;
            float v = (k < IND) ? xp[e] : 0.0f;
            union { __hip_bfloat16 h; short s; } u;
            u.h = __float2bfloat16(v);
            o[e] = u.s;
        }
        *(short8*)(Xh + (size_t)unit * 8) = o;
    }
}

__global__ void prep_w(const float* __restrict__ W, __hip_bfloat16* __restrict__ Wxh,
                       uint64_t* __restrict__ p1f, uint64_t* __restrict__ sums,
                       uint64_t* __restrict__ chunks) {
    if (blockIdx.x == 0) {       // zero exchange area every launch (replay + 0xAA poison)
        for (int i = threadIdx.x; i < 256; i += blockDim.x)
            __hip_atomic_store(&p1f[i], 0ull, __ATOMIC_RELAXED, AGENT);
        for (int i = threadIdx.x; i < 2 * 2 * 128; i += blockDim.x)
            __hip_atomic_store(&sums[i], 0ull, __ATOMIC_RELAXED, AGENT);
        for (int i = threadIdx.x; i < 2 * 2 * 128 * 16; i += blockDim.x)
            __hip_atomic_store(&chunks[i], 0ull, __ATOMIC_RELAXED, AGENT);
    }
    const int total = NCOL * KPAD;
    for (int idx = blockIdx.x * blockDim.x + threadIdx.x; idx < total; idx += gridDim.x * blockDim.x) {
        int k = idx % KPAD;
        int n = idx / KPAD;
        float v = (k < IND) ? W[(long)n * ISZ + k] : 0.0f;
        Wxh[idx] = __float2bfloat16(v);
    }
}

// Wst[h][n] = W[n][700+h]
__global__ __launch_bounds__(256) void prep_t(const float* __restrict__ W, float* __restrict__ Wst) {
    __shared__ float tile[32][33];
    const int h0 = blockIdx.x * 32, n0 = blockIdx.y * 32;
    const int tx = threadIdx.x, ty = threadIdx.y;
    #pragma unroll
    for (int j = 0; j < 32; j += 8)
        tile[ty + j][tx] = W[(long)(n0 + ty + j) * ISZ + IND + h0 + tx];
    __syncthreads();
    #pragma unroll
    for (int j = 0; j < 32; j += 8)
        Wst[(long)(h0 + ty + j) * NCOL + n0 + tx] = tile[tx][ty + j];
}

__global__ __launch_bounds__(256, 1) void snn_scan(
    const __hip_bfloat16* __restrict__ Xh, const __hip_bfloat16* __restrict__ Wxh,
    const float* __restrict__ Wst, uint64_t* __restrict__ p1f, uint64_t* __restrict__ sums,
    uint64_t* __restrict__ chunks,
    const float* __restrict__ bvec, const float* __restrict__ tau_m, const float* __restrict__ tau_n,
    const float* __restrict__ Wr, const float* __restrict__ brv, const float* __restrict__ tau_r,
    const float* __restrict__ mem0, float* __restrict__ out)
{
    __shared__ __align__(16) char smem[SM_TOTAL];
    __shared__ uint32_t stageW[16];
    __shared__ uint64_t roSnap[16];
    __shared__ unsigned fPollDone[2], fStgw[2], fCorr[2];
    __shared__ unsigned fRoSnap, anySpkF, dirtyH[2];

    __hip_bfloat16* Bp    = (__hip_bfloat16*)(smem + SM_BP);
    uint8_t*        Abuf  = (uint8_t*)(smem + SM_A2);      // phase1: 3 x 22528
    float*          curl1 = (float*)(smem + SM_CURL1);     // phase1: 2 x 2112 floats
    uint8_t*        Apre2 = (uint8_t*)(smem + SM_A2);      // phase2: 90112
    float*          curL2 = (float*)(smem + SM_CURL2);
    uint8_t*        mTb   = (uint8_t*)(smem + SM_MTB);

    const int wg    = blockIdx.x;
    const int rtile = wg & 7;         // rows [rtile*16, +16)  (== XCD under round-robin)
    const int ctile = wg >> 3;        // cols [ctile*128, +128) = neurons [ctile*32,+32)
    const int tid   = threadIdx.x;
    const int lane  = tid & 63, wid = tid >> 6;
    const int colA  = lane & 15, kb8 = (lane >> 4) * 8;

    if (tid < 2) { fPollDone[tid] = 0; fStgw[tid] = 0; fCorr[tid] = 0; dirtyH[tid] = 0; }
    if (tid == 0) { fRoSnap = 0; anySpkF = 0; }

    // readout consts (o = lane) — shared by both phases
    float r_alpha = 0.f, r_bias = 0.f, r_rmem = 0.f, r_acc = 0.f;
    const float* WrRow = Wr;
    if (wid == 0 && lane < 32) {
        int o = (lane < OUTD) ? lane : 0;
        r_alpha = sigmoidf(tau_r[o]);
        r_bias  = brv[o];
        WrRow   = Wr + o * HID;
    }
    const int roB1 = (ctile < 16) ? rtile * 16 + ctile : -1;   // phase-1 readout row

    // ---------------- phase-1 per-thread state: 2 neurons x 4 branches ----------------
    const int urow = tid >> 4;        // 0..15 local row
    const int nsel = tid & 15;        // neuron pair select
    const int b1   = rtile * 16 + urow;
    float dn[8], bt[8], omb[8], biasv[8], alph[2], oma[2], mem[2];
    #pragma unroll
    for (int m = 0; m < 2; ++m) {
        int i = ctile * 32 + nsel * 2 + m;
        alph[m] = sigmoidf(tau_m[i]);
        oma[m]  = 1.0f - alph[m];
        mem[m]  = mem0[b1 * HID + i];
        #pragma unroll
        for (int j = 0; j < 4; ++j) {
            bt[m * 4 + j]    = sigmoidf(tau_n[i * 4 + j]);
            omb[m * 4 + j]   = 1.0f - bt[m * 4 + j];
            biasv[m * 4 + j] = bvec[i * 4 + j];
            dn[m * 4 + j]    = 0.0f;
        }
    }

    // B panel -> registers, straight from global (176 VGPR/wave, asm-pinned vs remat)
    const int cbase = ctile * 128 + wid * 32;
    short8 Breg[44];
    #pragma unroll
    for (int i = 0; i < 22; ++i) {
        Breg[2 * i]     = *(const short8*)(Wxh + (long)(cbase + colA) * KPAD + i * 32 + kb8);
        Breg[2 * i + 1] = *(const short8*)(Wxh + (long)(cbase + 16 + colA) * KPAD + i * 32 + kb8);
    }
    asm volatile("s_waitcnt vmcnt(0)" ::: "memory");
    __builtin_amdgcn_sched_barrier(0);
    #pragma unroll
    for (int i = 0; i < 44; ++i) asm volatile("" : "+v"(Breg[i]));

    // ---------------- phase-1 A pipeline prologue ----------------
    const int    halfI    = rtile >> 2;
    const size_t sliceOff = (size_t)(rtile & 3) * 22528;
    const int    p1row    = lane & 15;
    const int    sw1      = p1row & 7;

    issueA(Xh, 0, halfI, sliceOff, Abuf, wid, lane);
    issueA(Xh, 1, halfI, sliceOff, Abuf + 22528, wid, lane);
    if (wid < 2) asm volatile("s_waitcnt vmcnt(6)" ::: "memory");
    else         asm volatile("s_waitcnt vmcnt(5)" ::: "memory");
    __builtin_amdgcn_sched_barrier(0);
    asm volatile("s_waitcnt lgkmcnt(0)" ::: "memory");
    __builtin_amdgcn_sched_barrier(0);
    __builtin_amdgcn_s_barrier();

    // ================= PHASE 1: optimistic free-run =================
    float memmax = -1e30f;
    int bR = 0;
    for (int t = 0; t < T_STEPS; ++t) {
        // 1. issue DMA[t+2] (2-step-ahead) + counted drain so A[t+1] lands for next iter
        if (t + 2 < T_STEPS) {
            const int bW = (bR + 2 >= 3) ? bR - 1 : bR + 2;
            issueA(Xh, t + 2, halfI, sliceOff, Abuf + bW * 22528, wid, lane);
            if (wid < 2) asm volatile("s_waitcnt vmcnt(6)" ::: "memory");
            else         asm volatile("s_waitcnt vmcnt(5)" ::: "memory");
        } else {
            asm volatile("s_waitcnt vmcnt(0)" ::: "memory");
        }
        __builtin_amdgcn_sched_barrier(0);

        // 2. MFMA: 16 rows x 128 cols, A from LDS buf[bR], B from regs
        f32x4 acc0 = {0, 0, 0, 0}, acc1 = {0, 0, 0, 0};
        const uint8_t* Ab = Abuf + bR * 22528;
        #pragma unroll
        for (int i = 0; i < 22; ++i) {
            int k8 = i * 4 + (lane >> 4);
            short8 f0 = *(const short8*)(Ab + ((p1row * 88 + (k8 ^ sw1)) << 4));
            acc0 = __builtin_amdgcn_mfma_f32_16x16x32_bf16(f0, Breg[2 * i], acc0, 0, 0, 0);
            acc1 = __builtin_amdgcn_mfma_f32_16x16x32_bf16(f0, Breg[2 * i + 1], acc1, 0, 0, 0);
        }

        // 3. C -> curl1[t&1] (dbuf -> single barrier/step)
        float* cw = curl1 + (t & 1) * 2112;
        const int crow0 = (lane >> 4) << 2;
        #pragma unroll
        for (int j = 0; j < 4; ++j) {
            cw[(crow0 + j) * 132 + wid * 32 + colA]      = acc0[j];
            cw[(crow0 + j) * 132 + wid * 32 + 16 + colA] = acc1[j];
        }
        asm volatile("s_waitcnt lgkmcnt(0)" ::: "memory");
        __builtin_amdgcn_sched_barrier(0);
        __builtin_amdgcn_s_barrier();

        // 4. zero-spike update (no -spk term; violation via memmax)
        {
            const float* cl = cw + urow * 132 + nsel * 8;
            f32x4 cv0 = *(const f32x4*)(cl);
            f32x4 cv1 = *(const f32x4*)(cl + 4);
            float clv[8];
            #pragma unroll
            for (int e = 0; e < 4; ++e) { clv[e] = cv0[e]; clv[4 + e] = cv1[e]; }
            #pragma unroll
            for (int m = 0; m < 2; ++m) {
                float lin = 0.f;
                #pragma unroll
                for (int j = 0; j < 4; ++j) {
                    int idx = m * 4 + j;
                    dn[idx] = bt[idx] * dn[idx] + omb[idx] * (clv[idx] + biasv[idx]);
                    lin += dn[idx];
                }
                float mm = alph[m] * mem[m] + oma[m] * lin;   // VTH=1; spk==0 assumed
                mem[m] = mm;
                memmax = fmaxf(memmax, mm);
            }
        }

        // 5. readout (rsum = 0 under zero-spike assumption)
        if (wid == 0 && roB1 >= 0 && lane < 32) {
            r_rmem = r_alpha * r_rmem + (1.0f - r_alpha) * r_bias;
            float vmax = (lane < OUTD) ? r_rmem : -__builtin_inff();
            #pragma unroll
            for (int d = 16; d > 0; d >>= 1) vmax = fmaxf(vmax, __shfl_xor(vmax, d, 32));
            float e = (lane < OUTD) ? expf(r_rmem - vmax) : 0.f;
            float ssum = e;
            #pragma unroll
            for (int d = 16; d > 0; d >>= 1) ssum += __shfl_xor(ssum, d, 32);
            if (t >= 1) r_acc += e / ssum;   // WARMUP=0
        }
        bR = (bR + 1 == 3) ? 0 : bR + 1;
    }

    // ---------------- verdict ----------------
    if (__any(memmax > 1.0f) && lane == 0) anySpkF = 1u;
    __syncthreads();
    if (tid == 0)
        __hip_atomic_store(p1f + rtile * 32 + ctile,
                           (1ull << 32) | (uint64_t)anySpkF, __ATOMIC_RELAXED, AGENT);
    {
        const uint64_t* fp = p1f + tid;   // 256 threads <-> 256 flags
        uint64_t v;
        for (;;) {
            v = __hip_atomic_load(fp, __ATOMIC_RELAXED, AGENT);
            if ((unsigned)(v >> 32) == 1u) break;
            __builtin_amdgcn_s_sleep(1);
        }
        if ((unsigned)v != 0u) dirtyH[tid >> 7] = 1u;   // idx<128 <=> rows 0..63
    }
    __syncthreads();
    if (!dirtyH[rtile >> 2] && wid == 0 && roB1 >= 0 && lane < OUTD)
        out[roB1 * OUTD + lane] = r_acc;   // my phase-1 rows' half is clean
    if (!dirtyH[wg >> 7]) return;          // my phase-2 half clean -> done

    // ================= PHASE 2: synchronous fallback (old decomposition, tags +1) ============
    r_rmem = 0.f; r_acc = 0.f;
    const int w2    = wg & 127;
    const int bhalf = wg >> 7;
    const int bbase = bhalf * 64;
    const int c0    = w2 * 32;
    const int i0    = w2 * 8;
    const int roB2  = (wg < 64) ? wg : ((wg >= 128 && wg < 192) ? wg - 64 : -1);

    // deferred staging: Bp (vectorized) + mTb zero
    for (int idx = tid; idx < 32 * 88; idx += WGT) {
        int col = idx / 88, m = idx % 88;
        *(short8*)(Bp + col * 712 + m * 8) = *(const short8*)(Wxh + (long)(c0 + col) * KPAD + m * 8);
    }
    for (int idx = tid; idx < 64 * 136 / 4; idx += WGT)
        ((uint32_t*)mTb)[idx] = 0u;

    const int mwid = wid - 2;
    const int st   = tid - 128;
    const int r2   = st >> 1;
    const int half = st & 1;
    float dn2[16], bt2[16], omb2[16], bias2[16], alph2[4], oma2[4], mem2[4], spk2[4];
    if (wid >= 2) {
        const int b2 = bbase + r2;
        #pragma unroll
        for (int n = 0; n < 4; ++n) {
            int i = i0 + half * 4 + n;
            alph2[n] = sigmoidf(tau_m[i]);
            oma2[n]  = 1.0f - alph2[n];
            mem2[n]  = mem0[b2 * HID + i];
            spk2[n]  = 0.0f;
            #pragma unroll
            for (int j = 0; j < 4; ++j) {
                int idx = n * 4 + j;
                bt2[idx]   = sigmoidf(tau_n[i * 4 + j]);
                omb2[idx]  = 1.0f - bt2[idx];
                bias2[idx] = bvec[i * 4 + j];
                dn2[idx]   = 0.0f;
            }
        }
    }
    const int trRow = mwid * 32;
    const int rb2   = trRow + (lane & 15);
    const int sw2   = rb2 & 7;
    uint8_t* dst2   = Apre2 + mwid * 45056;

    if (wid >= 2) {
        const char* gsrc = (const char*)Xh + ((size_t)bhalf * UPB) * 16 + (size_t)mwid * 45056;
        #pragma unroll
        for (int i = 0; i < 44; ++i)
            dma16(gsrc + i * 1024 + lane * 16, dst2 + i * 1024);
    }
    asm volatile("s_waitcnt vmcnt(0)" ::: "memory");
    __syncthreads();

    if (wid < 2) {
        // ---- poll waves ----
        const int plane = tid;
        for (int k = 1; k <= T_STEPS; ++k) {
            const size_t base = ((size_t)((k - 1) & 1) * 2 + bhalf) * 128 + plane;
            const unsigned want = (unsigned)(k + 1);
            uint64_t v;
            for (;;) {
                v = __hip_atomic_load(sums + base, __ATOMIC_RELAXED, AGENT);
                if ((unsigned)(v >> 32) == want) break;
                __builtin_amdgcn_s_sleep(1);
            }
            unsigned mysum = (unsigned)v;
            if (mysum) {
                if (wid == 1)
                    while (ldsLd(&fRoSnap) < (unsigned)(k - 1)) {}
                const uint64_t* rec = chunks + base * 16;
                uint8_t* col = mTb + plane;
                unsigned pend = mysum;
                while (pend) {
                    int c = __builtin_ctz(pend);
                    uint64_t cv = __hip_atomic_load(rec + c, __ATOMIC_RELAXED, AGENT);
                    if ((unsigned)(cv >> 32) == want) {
                        pend &= pend - 1;
                        unsigned pay = (unsigned)cv;
                        col[(4 * c + 0) * 136] = (uint8_t)(pay);
                        col[(4 * c + 1) * 136] = (uint8_t)(pay >> 8);
                        col[(4 * c + 2) * 136] = (uint8_t)(pay >> 16);
                        col[(4 * c + 3) * 136] = (uint8_t)(pay >> 24);
                    } else {
                        __builtin_amdgcn_s_sleep(1);
                    }
                }
            }
            const bool anyW = __any(mysum != 0u);
            if (lane == 0)
                ldsSt(&fPollDone[wid], ((unsigned)k << 1) | (anyW ? 1u : 0u));

            if (wid == 0) {
                while ((ldsLd(&fPollDone[1]) >> 1) < (unsigned)k) {}
                if (roB2 >= 0 && lane < 16)
                    roSnap[lane] = ((const uint64_t*)(mTb + (roB2 & 63) * 136))[lane];
                asm volatile("s_waitcnt lgkmcnt(0)" ::: "memory");
                if (lane == 0) ldsSt(&fRoSnap, (unsigned)k);
                if (roB2 >= 0 && lane < 32) {
                    float rsum = 0.f;
                    #pragma unroll 4
                    for (int q = 0; q < 16; ++q) {
                        uint64_t mword = roSnap[q];
                        while (mword) {
                            int h = (q << 6) + __builtin_ctzll(mword);
                            mword &= mword - 1;
                            rsum += WrRow[h];
                        }
                    }
                    r_rmem = r_alpha * r_rmem + (1.0f - r_alpha) * (rsum + r_bias);
                    float vmax = (lane < OUTD) ? r_rmem : -__builtin_inff();
                    #pragma unroll
                    for (int d = 16; d > 0; d >>= 1) vmax = fmaxf(vmax, __shfl_xor(vmax, d, 32));
                    float e = (lane < OUTD) ? expf(r_rmem - vmax) : 0.f;
                    float ssum = e;
                    #pragma unroll
                    for (int d = 16; d > 0; d >>= 1) ssum += __shfl_xor(ssum, d, 32);
                    if (k >= 2) r_acc += e / ssum;
                }
            }
        }
        if (wid == 0 && roB2 >= 0 && lane < OUTD) out[roB2 * OUTD + lane] = r_acc;
    } else {
        // ---- compute waves ----
        const float* clp = curL2 + r2 * 36 + half * 16;
        for (int t = 0; t < T_STEPS; ++t) {
            f32x4 a00 = {0,0,0,0}, a01 = {0,0,0,0}, a10 = {0,0,0,0}, a11 = {0,0,0,0};
            #pragma unroll
            for (int k0 = 0; k0 < KPAD; k0 += 32) {
                int k8 = (k0 >> 3) + (lane >> 4);
                short8 f0 = *(const short8*)&Apre2[(((rb2)      * 88 + (k8 ^ sw2)) << 4)];
                short8 f1 = *(const short8*)&Apre2[(((rb2 + 16) * 88 + (k8 ^ sw2)) << 4)];
                short8 b0 = *(const short8*)(&Bp[(colA) * 712 + k0 + kb8]);
                short8 b1 = *(const short8*)(&Bp[(16 + colA) * 712 + k0 + kb8]);
                a00 = __builtin_amdgcn_mfma_f32_16x16x32_bf16(f0, b0, a00, 0, 0, 0);
                a01 = __builtin_amdgcn_mfma_f32_16x16x32_bf16(f0, b1, a01, 0, 0, 0);
                a10 = __builtin_amdgcn_mfma_f32_16x16x32_bf16(f1, b0, a10, 0, 0, 0);
                a11 = __builtin_amdgcn_mfma_f32_16x16x32_bf16(f1, b1, a11, 0, 0, 0);
            }
            asm volatile("s_waitcnt lgkmcnt(0)" ::: "memory");
            __builtin_amdgcn_sched_barrier(0);
            if (t + 1 < T_STEPS) {
                const char* gsrc = (const char*)Xh
                    + (((size_t)(t + 1) * 2 + bhalf) * UPB) * 16 + (size_t)mwid * 45056;
                #pragma unroll
                for (int i = 0; i < 44; ++i)
                    dma16(gsrc + i * 1024 + lane * 16, dst2 + i * 1024);
            }
            {
                const int crow0 = trRow + ((lane >> 4) << 2);
                #pragma unroll
                for (int j = 0; j < 4; ++j) {
                    curL2[(crow0 + j) * 36 + colA]           = a00[j];
                    curL2[(crow0 + j) * 36 + 16 + colA]      = a01[j];
                    curL2[(crow0 + 16 + j) * 36 + colA]      = a10[j];
                    curL2[(crow0 + 16 + j) * 36 + 16 + colA] = a11[j];
                }
            }
            asm volatile("s_waitcnt lgkmcnt(0)" ::: "memory");
            __builtin_amdgcn_sched_barrier(0);

            f32x4 cv0 = *(const f32x4*)(clp + 0);
            f32x4 cv1 = *(const f32x4*)(clp + 4);
            f32x4 cv2 = *(const f32x4*)(clp + 8);
            f32x4 cv3 = *(const f32x4*)(clp + 12);
            float cl[16];
            #pragma unroll
            for (int e = 0; e < 4; ++e) {
                cl[e] = cv0[e]; cl[4 + e] = cv1[e]; cl[8 + e] = cv2[e]; cl[12 + e] = cv3[e];
            }
            float memS[4], spkS[4];
            #pragma unroll
            for (int n = 0; n < 4; ++n) {
                float lin = 0.f;
                #pragma unroll
                for (int j = 0; j < 4; ++j) {
                    int idx = n * 4 + j;
                    dn2[idx] = bt2[idx] * dn2[idx] + omb2[idx] * (cl[idx] + bias2[idx]);
                    lin += dn2[idx];
                }
                memS[n] = alph2[n] * mem2[n] + oma2[n] * lin - spk2[n];
                spkS[n] = (memS[n] > 1.0f) ? 1.0f : 0.0f;
            }
            unsigned nib = 0;
            #pragma unroll
            for (int n = 0; n < 4; ++n) nib |= (spkS[n] != 0.f ? 1u : 0u) << (half * 4 + n);
            nib |= (unsigned)__shfl_xor((int)nib, 1);
            if (half == 0) ((uint8_t*)stageW)[r2] = (uint8_t)nib;
            if (lane == 0) ldsSt(&fStgw[mwid], (unsigned)(t + 1));

            bool anySpk = false;
            if (t > 0) {
                unsigned p0, p1;
                do { p0 = ldsLd(&fPollDone[0]); } while ((p0 >> 1) < (unsigned)t);
                do { p1 = ldsLd(&fPollDone[1]); } while ((p1 >> 1) < (unsigned)t);
                anySpk = ((p0 | p1) & 1u) != 0u;
            }
            if (anySpk) {
                float recv[16];
                #pragma unroll
                for (int e = 0; e < 16; ++e) recv[e] = 0.f;
                const float* Wb = Wst + c0 + half * 16;
                const uint64_t* mrow = (const uint64_t*)(mTb + r2 * 136);
                for (int q = 0; q < 16; ++q) {
                    uint64_t mword = mrow[q];
                    while (mword) {
                        int h = (q << 6) + __builtin_ctzll(mword);
                        mword &= mword - 1;
                        const f32x4* wv = (const f32x4*)(Wb + (long)h * NCOL);
                        f32x4 w0 = wv[0], w1 = wv[1], w2v = wv[2], w3 = wv[3];
                        #pragma unroll
                        for (int e = 0; e < 4; ++e) {
                            recv[e] += w0[e]; recv[4 + e] += w1[e];
                            recv[8 + e] += w2v[e]; recv[12 + e] += w3[e];
                        }
                    }
                }
                #pragma unroll
                for (int n = 0; n < 4; ++n) {
                    float cs = 0.f;
                    #pragma unroll
                    for (int j = 0; j < 4; ++j) {
                        int idx = n * 4 + j;
                        float ad = omb2[idx] * recv[idx];
                        dn2[idx] += ad; cs += ad;
                    }
                    memS[n] += oma2[n] * cs;
                    spkS[n] = (memS[n] > 1.0f) ? 1.0f : 0.0f;
                }
                unsigned nib2 = 0;
                #pragma unroll
                for (int n = 0; n < 4; ++n) nib2 |= (spkS[n] != 0.f ? 1u : 0u) << (half * 4 + n);
                nib2 |= (unsigned)__shfl_xor((int)nib2, 1);
                if (half == 0) ((uint8_t*)stageW)[r2] = (uint8_t)nib2;
                if (roB2 >= 0) while (ldsLd(&fRoSnap) < (unsigned)t) {}
                uint64_t* mz = (uint64_t*)(mTb + r2 * 136) + half * 8;
                #pragma unroll
                for (int e = 0; e < 8; ++e) mz[e] = 0;
                if (lane == 0) ldsSt(&fCorr[mwid], (unsigned)(t + 1));
            }
            #pragma unroll
            for (int n = 0; n < 4; ++n) { mem2[n] = memS[n]; spk2[n] = spkS[n]; }

            if (mwid == 0) {
                while (ldsLd(&fStgw[1]) < (unsigned)(t + 1)) {}
                if (anySpk) while (ldsLd(&fCorr[1]) < (unsigned)(t + 1)) {}
                unsigned pay = (lane < 16) ? stageW[lane] : 0u;
                const size_t pbase = ((size_t)(t & 1) * 2 + bhalf) * 128 + w2;
                if (lane < 16 && pay)
                    __hip_atomic_store(chunks + pbase * 16 + lane,
                                       ((uint64_t)(unsigned)(t + 2) << 32) | (uint64_t)pay,
                                       __ATOMIC_RELAXED, AGENT);
                uint64_t bal = __ballot(pay != 0u);
                if (lane == 0)
                    __hip_atomic_store(sums + pbase,
                                       ((uint64_t)(unsigned)(t + 2) << 32) | (uint64_t)(bal & 0xFFFFull),
                                       __ATOMIC_RELAXED, AGENT);
            }
            asm volatile("s_waitcnt vmcnt(0)" ::: "memory");
        }
    }
}

extern "C" void kernel_launch(void* const* d_in, const int* in_sizes, int n_in,
                              void* d_out, int out_size, void* d_ws, size_t ws_size,
                              hipStream_t stream) {
    (void)in_sizes; (void)n_in; (void)out_size; (void)ws_size;
    const float* x     = (const float*)d_in[0];
    const float* W     = (const float*)d_in[1];
    const float* bv    = (const float*)d_in[2];
    const float* tau_m = (const float*)d_in[3];
    const float* tau_n = (const float*)d_in[4];
    const float* Wr    = (const float*)d_in[5];
    const float* br    = (const float*)d_in[6];
    const float* tau_r = (const float*)d_in[7];
    const float* mem0  = (const float*)d_in[8];

    char* ws = (char*)d_ws;
    uint64_t*        p1flag = (uint64_t*)(ws + O_P1F);
    uint64_t*        sums   = (uint64_t*)(ws + O_SUM);
    uint64_t*        chunks = (uint64_t*)(ws + O_CHK);
    float*           Wst    = (float*)(ws + O_WST);
    __hip_bfloat16*  Wxh    = (__hip_bfloat16*)(ws + O_WXH);
    __hip_bfloat16*  Xh     = (__hip_bfloat16*)(ws + O_XH);

    prep_x<<<2048, 256, 0, stream>>>(x, Xh);
    prep_w<<<2048, 256, 0, stream>>>(W, Wxh, p1flag, sums, chunks);
    dim3 g3(32, 128), b3(32, 8);
    prep_t<<<g3, b3, 0, stream>>>(W, Wst);
    snn_scan<<<NWG, WGT, 0, stream>>>(Xh, Wxh, Wst, p1flag, sums, chunks,
                                      bv, tau_m, tau_n, Wr, br, tau_r, mem0, (float*)d_out);
}